// Round 6
// baseline (88.718 us; speedup 1.0000x reference)
//
#include <hip/hip_runtime.h>
#include <hip/hip_bf16.h>

typedef __attribute__((ext_vector_type(8))) short bf16x8;
typedef __attribute__((ext_vector_type(4))) float f32x4;

static __device__ __forceinline__ unsigned short f2bf(float f) {
    unsigned int u = __float_as_uint(f);
    unsigned int rnd = 0x7FFFu + ((u >> 16) & 1u);
    return (unsigned short)((u + rnd) >> 16);
}

// pack two f32 -> 2xbf16 (RNE) using v_cvt_pk_bf16_f32
static __device__ __forceinline__ bf16x8 cvt8(float4 u, float4 v) {
    union { bf16x8 r; __hip_bfloat162 h[4]; } o;
    o.h[0] = __float22bfloat162_rn(float2{u.x, u.y});
    o.h[1] = __float22bfloat162_rn(float2{u.z, u.w});
    o.h[2] = __float22bfloat162_rn(float2{v.x, v.y});
    o.h[3] = __float22bfloat162_rn(float2{v.z, v.w});
    return o.r;
}

// ---------------- Kernel 1: hypernetwork hw = hyper@W1+b1, bias = hyper@Wb+bb
__global__ __launch_bounds__(256)
void hypernet_kernel(const float* __restrict__ hyper,   // (8,256)
                     const float* __restrict__ W1,      // (256,4096)
                     const float* __restrict__ b1,      // (4096)
                     const float* __restrict__ Wb,      // (256,64)
                     const float* __restrict__ bb,      // (64)
                     float* __restrict__ hw,            // ws: 8*4096
                     float* __restrict__ bias)          // ws: 8*64
{
    __shared__ float red[256];
    const int tid = threadIdx.x;
    const int p   = tid >> 5;          // 0..7  (d-range)
    const int jj  = tid & 31;          // 0..31 (output within block)
    const int o0  = blockIdx.x * 32;
    const int o   = o0 + jj;

    float acc = 0.f;
    if (o0 < 8 * 4096) {               // hw part (uniform per block)
        int h = o >> 12, j = o & 4095;
        const float* hr = hyper + (h << 8);
        #pragma unroll
        for (int i = 0; i < 32; ++i) {
            int d = (p << 5) + i;
            acc += hr[d] * W1[d * 4096 + j];
        }
    } else {                           // bias part
        int t = o - 8 * 4096;          // 0..511
        int h = t >> 6, s = t & 63;
        const float* hr = hyper + (h << 8);
        #pragma unroll
        for (int i = 0; i < 32; ++i) {
            int d = (p << 5) + i;
            acc += hr[d] * Wb[d * 64 + s];
        }
    }
    red[tid] = acc;
    __syncthreads();
    if (p == 0) {
        float sum = red[jj]       + red[32 + jj]  + red[64 + jj]  + red[96 + jj]
                  + red[128 + jj] + red[160 + jj] + red[192 + jj] + red[224 + jj];
        if (o0 < 8 * 4096) hw[o] = sum + b1[o & 4095];
        else {
            int t = o - 8 * 4096;
            bias[t] = sum + bb[t & 63];
        }
    }
}

// ---------------- Kernel 2: W[h] = down@up, packed directly into MFMA
// B-fragment order for v_mfma_f32_16x16x32_bf16 (validated in round 1).
__global__ void pack_kernel(const float* __restrict__ hw,          // 8*4096
                            unsigned short* __restrict__ packed)   // 32768 bf16
{
    int p = blockIdx.x * blockDim.x + threadIdx.x;  // 0..32767
    int b   = p & 7;
    int l   = (p >> 3) & 63;
    int kap = (p >> 9) & 1;
    int n   = p >> 10;                              // 0..31
    int k   = kap * 32 + ((l >> 4) << 3) + b;       // 0..63 (= target feature d)
    int col = (n << 4) + (l & 15);                  // 0..511
    int h = col >> 6, s = col & 63;
    const float* hwh = hw + h * 4096;
    float acc = 0.f;
    #pragma unroll
    for (int r = 0; r < 32; ++r)
        acc += hwh[k * 32 + r] * hwh[2048 + r * 64 + s];
    packed[p] = f2bf(acc);
}

// ---------------- Kernel 3: main — block-shared LDS-staged streaming GEMM.
// 1024 blocks = exactly 4/CU at __launch_bounds__(256,4). Block covers 128
// rows as 4 groups of 32. Per group: X (32x64 f32, XOR-swizzled) staged ONCE
// in LDS shared by all 4 waves (kills the 4x redundant X reads of rounds 2-4),
// double-buffered with T14 split (load g+1 early, ds_write late, 1 barrier).
// h-split accumulation keeps unified regs < 128. Bias folded as MFMA C-init.
#define GR 32

__global__ __launch_bounds__(256, 4)
void main_kernel(const float* __restrict__ X,       // (M,64)
                 const float* __restrict__ Mask,    // (M,8)
                 const unsigned short* __restrict__ packedB,
                 const float* __restrict__ bias,    // (8,64)
                 float* __restrict__ Out,           // (M,64)
                 int M)
{
    __shared__ __align__(16) float sX[2][GR * 64];  // 16 KB, swizzled
    __shared__ __align__(16) float sM[2][GR * 12];  // 3 KB, stride-12 padded

    const int tid  = threadIdx.x;
    const int lane = tid & 63;
    const int w    = tid >> 6;          // wave id -> output col tile
    const int c    = lane & 15;         // A row-within-tile / D col-within-tile
    const int g    = lane >> 4;         // k-group / D row-group
    const int s    = (w << 4) + c;      // output column 0..63

    const int rowsPerBlock = M / gridDim.x;   // 128
    const int ngrp = rowsPerBlock / GR;       // 4
    const int blockRow = blockIdx.x * rowsPerBlock;

    // staging map: thread -> (row, 8 contiguous logical words, swizzled store)
    const int srow = tid >> 3;                          // 0..31
    const int sw8  = (tid & 7) << 3;                    // stored word base
    const int xoff = srow * 64 + (sw8 ^ ((srow & 7) << 3)); // logical src word
    const int sxw  = srow * 64 + sw8;                   // LDS stored word
    const int smw  = (tid >> 3) * 12 + (tid & 7);       // mask LDS word

    // ---- prologue: issue group-0 staging loads
    float4 p0 = *(const float4*)(X + blockRow * 64 + xoff);
    float4 p1 = *(const float4*)(X + blockRow * 64 + xoff + 4);
    float  pm = Mask[blockRow * 8 + tid];

    // ---- B fragments (loaded once per wave)
    bf16x8 Bf[8][2];
    #pragma unroll
    for (int h = 0; h < 8; ++h) {
        const unsigned short* pb = packedB + ((((h * 4 + w) * 2) * 64) + lane) * 8;
        Bf[h][0] = *(const bf16x8*)pb;
        Bf[h][1] = *(const bf16x8*)(pb + 512);
    }
    // ---- bias for this lane's output column (C-init values)
    float biasr[8];
    #pragma unroll
    for (int h = 0; h < 8; ++h) biasr[h] = bias[h * 64 + s];

    // publish group 0
    *(float4*)(&sX[0][sxw])     = p0;
    *(float4*)(&sX[0][sxw + 4]) = p1;
    sM[0][smw] = pm;
    __syncthreads();

    int buf = 0;
    for (int grp = 0; grp < ngrp; ++grp) {
        const int gRow = blockRow + grp * GR;
        const bool more = (grp + 1 < ngrp);

        // issue next group's staging loads (land during this group's compute)
        if (more) {
            const float* xb = X + (gRow + GR) * 64;
            p0 = *(const float4*)(xb + xoff);
            p1 = *(const float4*)(xb + xoff + 4);
            pm = Mask[(gRow + GR) * 8 + tid];
        }

        const float* sx = sX[buf];
        const float* sm = sM[buf];
        const int sz = (c & 7) << 3;    // read-side XOR swizzle

        #pragma unroll
        for (int t = 0; t < 2; ++t) {
            const int rb = ((t << 4) + c) * 64;
            float4 x0 = *(const float4*)(&sx[rb + (((g << 3)     ) ^ sz)]);
            float4 x1 = *(const float4*)(&sx[rb + (((g << 3)     ) ^ sz) + 4]);
            float4 x2 = *(const float4*)(&sx[rb + (((g << 3) + 32) ^ sz)]);
            float4 x3 = *(const float4*)(&sx[rb + (((g << 3) + 32) ^ sz) + 4]);

            bf16x8 a0 = cvt8(x0, x1);   // logical cols [g*8, g*8+8)
            bf16x8 a1 = cvt8(x2, x3);   // logical cols [32+g*8, ...)

            float o[4];
            // ---- half 1: h = 0..3 (acc live: 16 regs)
            {
                f32x4 acc[4];
                #pragma unroll
                for (int h = 0; h < 4; ++h) acc[h] = (f32x4)(biasr[h]);
                #pragma unroll
                for (int h = 0; h < 4; ++h) {
                    acc[h] = __builtin_amdgcn_mfma_f32_16x16x32_bf16(a0, Bf[h][0], acc[h], 0, 0, 0);
                    acc[h] = __builtin_amdgcn_mfma_f32_16x16x32_bf16(a1, Bf[h][1], acc[h], 0, 0, 0);
                }
                #pragma unroll
                for (int i = 0; i < 4; ++i) {
                    const int rr = (t << 4) + (g << 2) + i;
                    const float4 ml = *(const float4*)(&sm[rr * 12]);
                    float v = ml.x * acc[0][i];
                    v = fmaf(ml.y, acc[1][i], v);
                    v = fmaf(ml.z, acc[2][i], v);
                    v = fmaf(ml.w, acc[3][i], v);
                    o[i] = v;
                }
            }
            // ---- half 2: h = 4..7
            {
                f32x4 acc[4];
                #pragma unroll
                for (int h = 0; h < 4; ++h) acc[h] = (f32x4)(biasr[4 + h]);
                #pragma unroll
                for (int h = 0; h < 4; ++h) {
                    acc[h] = __builtin_amdgcn_mfma_f32_16x16x32_bf16(a0, Bf[4 + h][0], acc[h], 0, 0, 0);
                    acc[h] = __builtin_amdgcn_mfma_f32_16x16x32_bf16(a1, Bf[4 + h][1], acc[h], 0, 0, 0);
                }
                #pragma unroll
                for (int i = 0; i < 4; ++i) {
                    const int rr = (t << 4) + (g << 2) + i;
                    const float4 mh = *(const float4*)(&sm[rr * 12 + 4]);
                    float v = o[i];
                    v = fmaf(mh.x, acc[0][i], v);
                    v = fmaf(mh.y, acc[1][i], v);
                    v = fmaf(mh.z, acc[2][i], v);
                    v = fmaf(mh.w, acc[3][i], v);
                    Out[(gRow + rr) * 64 + s] = v;
                }
            }
        }

        // publish next group into the other buffer, then one barrier
        if (more) {
            float* sxn = sX[buf ^ 1];
            *(float4*)(&sxn[sxw])     = p0;
            *(float4*)(&sxn[sxw + 4]) = p1;
            sM[buf ^ 1][smw] = pm;
        }
        __syncthreads();
        buf ^= 1;
    }
}

extern "C" void kernel_launch(void* const* d_in, const int* in_sizes, int n_in,
                              void* d_out, int out_size, void* d_ws, size_t ws_size,
                              hipStream_t stream) {
    const float* target = (const float*)d_in[0];   // (B,L,64)
    const float* hyper  = (const float*)d_in[1];   // (8,256)
    const float* mask   = (const float*)d_in[2];   // (B,L,8)
    const float* W1     = (const float*)d_in[3];   // (256,4096)
    const float* b1     = (const float*)d_in[4];   // (4096)
    const float* Wb     = (const float*)d_in[5];   // (256,64)
    const float* bb     = (const float*)d_in[6];   // (64)
    float* out = (float*)d_out;

    float* hw   = (float*)d_ws;                         // 32768 f32
    float* bias = hw + 8 * 4096;                        // 512 f32
    unsigned short* packed = (unsigned short*)(bias + 512); // 32768 bf16

    const int M = in_sizes[0] / 64;                     // 131072 rows

    hipLaunchKernelGGL(hypernet_kernel, dim3((8 * 4096 + 8 * 64) / 32), dim3(256),
                       0, stream, hyper, W1, b1, Wb, bb, hw, bias);
    hipLaunchKernelGGL(pack_kernel, dim3(32768 / 256), dim3(256), 0, stream, hw, packed);
    hipLaunchKernelGGL(main_kernel, dim3(1024), dim3(256), 0, stream,
                       target, mask, packed, bias, out, M);
}

// Round 7
// 37.281 us; speedup vs baseline: 2.3797x; 2.3797x over previous
//
#include <hip/hip_runtime.h>
#include <hip/hip_bf16.h>

typedef __attribute__((ext_vector_type(8))) short bf16x8;
typedef __attribute__((ext_vector_type(4))) float f32x4;

static __device__ __forceinline__ unsigned short f2bf(float f) {
    unsigned int u = __float_as_uint(f);
    unsigned int rnd = 0x7FFFu + ((u >> 16) & 1u);
    return (unsigned short)((u + rnd) >> 16);
}

// pack two f32 -> 2xbf16 (RNE) using v_cvt_pk_bf16_f32
static __device__ __forceinline__ bf16x8 cvt8(float4 u, float4 v) {
    union { bf16x8 r; __hip_bfloat162 h[4]; } o;
    o.h[0] = __float22bfloat162_rn(float2{u.x, u.y});
    o.h[1] = __float22bfloat162_rn(float2{u.z, u.w});
    o.h[2] = __float22bfloat162_rn(float2{v.x, v.y});
    o.h[3] = __float22bfloat162_rn(float2{v.z, v.w});
    return o.r;
}

// ---------------- Kernel 1: hypernetwork hw = hyper@W1+b1, bias = hyper@Wb+bb
__global__ __launch_bounds__(256)
void hypernet_kernel(const float* __restrict__ hyper,   // (8,256)
                     const float* __restrict__ W1,      // (256,4096)
                     const float* __restrict__ b1,      // (4096)
                     const float* __restrict__ Wb,      // (256,64)
                     const float* __restrict__ bb,      // (64)
                     float* __restrict__ hw,            // ws: 8*4096
                     float* __restrict__ bias)          // ws: 8*64
{
    __shared__ float red[256];
    const int tid = threadIdx.x;
    const int p   = tid >> 5;          // 0..7  (d-range)
    const int jj  = tid & 31;          // 0..31 (output within block)
    const int o0  = blockIdx.x * 32;
    const int o   = o0 + jj;

    float acc = 0.f;
    if (o0 < 8 * 4096) {               // hw part (uniform per block)
        int h = o >> 12, j = o & 4095;
        const float* hr = hyper + (h << 8);
        #pragma unroll
        for (int i = 0; i < 32; ++i) {
            int d = (p << 5) + i;
            acc += hr[d] * W1[d * 4096 + j];
        }
    } else {                           // bias part
        int t = o - 8 * 4096;          // 0..511
        int h = t >> 6, s = t & 63;
        const float* hr = hyper + (h << 8);
        #pragma unroll
        for (int i = 0; i < 32; ++i) {
            int d = (p << 5) + i;
            acc += hr[d] * Wb[d * 64 + s];
        }
    }
    red[tid] = acc;
    __syncthreads();
    if (p == 0) {
        float sum = red[jj]       + red[32 + jj]  + red[64 + jj]  + red[96 + jj]
                  + red[128 + jj] + red[160 + jj] + red[192 + jj] + red[224 + jj];
        if (o0 < 8 * 4096) hw[o] = sum + b1[o & 4095];
        else {
            int t = o - 8 * 4096;
            bias[t] = sum + bb[t & 63];
        }
    }
}

// ---------------- Kernel 2: W[h] = down@up, packed directly into MFMA
// B-fragment order for v_mfma_f32_16x16x32_bf16 (validated in round 1).
__global__ void pack_kernel(const float* __restrict__ hw,          // 8*4096
                            unsigned short* __restrict__ packed)   // 32768 bf16
{
    int p = blockIdx.x * blockDim.x + threadIdx.x;  // 0..32767
    int b   = p & 7;
    int l   = (p >> 3) & 63;
    int kap = (p >> 9) & 1;
    int n   = p >> 10;                              // 0..31
    int k   = kap * 32 + ((l >> 4) << 3) + b;       // 0..63 (= target feature d)
    int col = (n << 4) + (l & 15);                  // 0..511
    int h = col >> 6, s = col & 63;
    const float* hwh = hw + h * 4096;
    float acc = 0.f;
    #pragma unroll
    for (int r = 0; r < 32; ++r)
        acc += hwh[k * 32 + r] * hwh[2048 + r * 64 + s];
    packed[p] = f2bf(acc);
}

// ---------------- Kernel 3: main — block-shared LDS-staged streaming GEMM.
// 1024 blocks x 128 rows (4 groups of 32), 3 waves/SIMD (never 4: Bf=64 regs,
// cap 128 spills — rounds 3/5/6). X staged via LDS: tid-linear global loads
// (perfect coalescing), write-side XOR swizzle granule^=(row&7)<<1 -> balanced
// 8 words/bank on ds_write AND ds_read. Double-buffered, T14 split (issue
// next-group loads before compute, ds_write after), ONE barrier per group.
// h-split accumulation; bias folded as MFMA C-init; masks in stride-12 LDS.
#define GR 32

__global__ __launch_bounds__(256, 3)
void main_kernel(const float* __restrict__ X,       // (M,64)
                 const float* __restrict__ Mask,    // (M,8)
                 const unsigned short* __restrict__ packedB,
                 const float* __restrict__ bias,    // (8,64)
                 float* __restrict__ Out,           // (M,64)
                 int M)
{
    __shared__ __align__(16) float sX[2][GR * 64];  // 16 KB, swizzled
    __shared__ __align__(16) float sM[2][GR * 12];  // 3 KB, stride-12 padded

    const int tid  = threadIdx.x;
    const int lane = tid & 63;
    const int w    = tid >> 6;          // wave id -> output col tile
    const int c    = lane & 15;         // A row-within-tile / D col-within-tile
    const int g    = lane >> 4;         // k-group / D row-group
    const int s    = (w << 4) + c;      // output column 0..63

    const int rowsPerBlock = M / gridDim.x;   // 128
    const int ngrp = rowsPerBlock / GR;       // 4
    const int blockRow = blockIdx.x * rowsPerBlock;

    // ---- staging map (two float4 per thread, lane-contiguous global reads)
    // f in {tid, tid+256}: row = f>>4 (0..31), q = f&15 (16B quad within row)
    const int row0 = tid >> 4,        q0 = tid & 15;
    const int row1 = (tid + 256) >> 4, q1 = tid & 15;
    // global word offsets (linear)
    const int gx0 = row0 * 64 + q0 * 4;
    const int gx1 = row1 * 64 + q1 * 4;
    // LDS word offsets (swizzled: 4-word granule index ^= (row&7)<<1)
    const int lx0 = row0 * 64 + ((q0 ^ ((row0 & 7) << 1)) << 2);
    const int lx1 = row1 * 64 + ((q1 ^ ((row1 & 7) << 1)) << 2);
    const int smw = (tid >> 3) * 12 + (tid & 7);       // mask LDS word

    // ---- prologue: issue group-0 staging loads
    float4 p0 = *(const float4*)(X + blockRow * 64 + gx0);
    float4 p1 = *(const float4*)(X + blockRow * 64 + gx1);
    float  pm = Mask[blockRow * 8 + tid];

    // ---- B fragments (loaded once per wave; lane-contiguous, L2-hot)
    bf16x8 Bf[8][2];
    #pragma unroll
    for (int h = 0; h < 8; ++h) {
        const unsigned short* pb = packedB + ((((h * 4 + w) * 2) * 64) + lane) * 8;
        Bf[h][0] = *(const bf16x8*)pb;
        Bf[h][1] = *(const bf16x8*)(pb + 512);
    }
    // ---- bias for this lane's output column (C-init values)
    float biasr[8];
    #pragma unroll
    for (int h = 0; h < 8; ++h) biasr[h] = bias[h * 64 + s];

    // publish group 0
    *(float4*)(&sX[0][lx0]) = p0;
    *(float4*)(&sX[0][lx1]) = p1;
    sM[0][smw] = pm;
    __syncthreads();

    // read-side swizzle: logical word base ^ ((c&7)*8), bijective vs write side
    const int sz = (c & 7) << 3;

    int buf = 0;
    for (int grp = 0; grp < ngrp; ++grp) {
        const int gRow = blockRow + grp * GR;
        const bool more = (grp + 1 < ngrp);

        // T14: issue next group's staging loads (land during this compute)
        if (more) {
            const float* xb = X + (gRow + GR) * 64;
            p0 = *(const float4*)(xb + gx0);
            p1 = *(const float4*)(xb + gx1);
            pm = Mask[(gRow + GR) * 8 + tid];
        }

        const float* sx = sX[buf];
        const float* sm = sM[buf];

        #pragma unroll
        for (int t = 0; t < 2; ++t) {
            const int rb = ((t << 4) + c) * 64;
            float4 x0 = *(const float4*)(&sx[rb + (((g << 3)     ) ^ sz)]);
            float4 x1 = *(const float4*)(&sx[rb + ((((g << 3)     ) ^ sz) + 4)]);
            float4 x2 = *(const float4*)(&sx[rb + (((g << 3) + 32) ^ sz)]);
            float4 x3 = *(const float4*)(&sx[rb + ((((g << 3) + 32) ^ sz) + 4)]);

            bf16x8 a0 = cvt8(x0, x1);   // logical cols [g*8, g*8+8)
            bf16x8 a1 = cvt8(x2, x3);   // logical cols [32+g*8, ...)

            float o[4];
            // ---- half 1: h = 0..3 (acc live: 16 regs)
            {
                f32x4 acc[4];
                #pragma unroll
                for (int h = 0; h < 4; ++h) acc[h] = (f32x4)(biasr[h]);
                #pragma unroll
                for (int h = 0; h < 4; ++h) {
                    acc[h] = __builtin_amdgcn_mfma_f32_16x16x32_bf16(a0, Bf[h][0], acc[h], 0, 0, 0);
                    acc[h] = __builtin_amdgcn_mfma_f32_16x16x32_bf16(a1, Bf[h][1], acc[h], 0, 0, 0);
                }
                #pragma unroll
                for (int i = 0; i < 4; ++i) {
                    const int rr = (t << 4) + (g << 2) + i;
                    const float4 ml = *(const float4*)(&sm[rr * 12]);
                    float v = ml.x * acc[0][i];
                    v = fmaf(ml.y, acc[1][i], v);
                    v = fmaf(ml.z, acc[2][i], v);
                    v = fmaf(ml.w, acc[3][i], v);
                    o[i] = v;
                }
            }
            // ---- half 2: h = 4..7
            {
                f32x4 acc[4];
                #pragma unroll
                for (int h = 0; h < 4; ++h) acc[h] = (f32x4)(biasr[4 + h]);
                #pragma unroll
                for (int h = 0; h < 4; ++h) {
                    acc[h] = __builtin_amdgcn_mfma_f32_16x16x32_bf16(a0, Bf[4 + h][0], acc[h], 0, 0, 0);
                    acc[h] = __builtin_amdgcn_mfma_f32_16x16x32_bf16(a1, Bf[4 + h][1], acc[h], 0, 0, 0);
                }
                #pragma unroll
                for (int i = 0; i < 4; ++i) {
                    const int rr = (t << 4) + (g << 2) + i;
                    const float4 mh = *(const float4*)(&sm[rr * 12 + 4]);
                    float v = o[i];
                    v = fmaf(mh.x, acc[0][i], v);
                    v = fmaf(mh.y, acc[1][i], v);
                    v = fmaf(mh.z, acc[2][i], v);
                    v = fmaf(mh.w, acc[3][i], v);
                    Out[(gRow + rr) * 64 + s] = v;
                }
            }
        }

        // publish next group into the other buffer, then one barrier
        if (more) {
            float* sxn = sX[buf ^ 1];
            *(float4*)(&sxn[lx0]) = p0;
            *(float4*)(&sxn[lx1]) = p1;
            sM[buf ^ 1][smw] = pm;
        }
        __syncthreads();
        buf ^= 1;
    }
}

extern "C" void kernel_launch(void* const* d_in, const int* in_sizes, int n_in,
                              void* d_out, int out_size, void* d_ws, size_t ws_size,
                              hipStream_t stream) {
    const float* target = (const float*)d_in[0];   // (B,L,64)
    const float* hyper  = (const float*)d_in[1];   // (8,256)
    const float* mask   = (const float*)d_in[2];   // (B,L,8)
    const float* W1     = (const float*)d_in[3];   // (256,4096)
    const float* b1     = (const float*)d_in[4];   // (4096)
    const float* Wb     = (const float*)d_in[5];   // (256,64)
    const float* bb     = (const float*)d_in[6];   // (64)
    float* out = (float*)d_out;

    float* hw   = (float*)d_ws;                         // 32768 f32
    float* bias = hw + 8 * 4096;                        // 512 f32
    unsigned short* packed = (unsigned short*)(bias + 512); // 32768 bf16

    const int M = in_sizes[0] / 64;                     // 131072 rows

    hipLaunchKernelGGL(hypernet_kernel, dim3((8 * 4096 + 8 * 64) / 32), dim3(256),
                       0, stream, hyper, W1, b1, Wb, bb, hw, bias);
    hipLaunchKernelGGL(pack_kernel, dim3(32768 / 256), dim3(256), 0, stream, hw, packed);
    hipLaunchKernelGGL(main_kernel, dim3(1024), dim3(256), 0, stream,
                       target, mask, packed, bias, out, M);
}